// Round 2
// baseline (1127.316 us; speedup 1.0000x reference)
//
#include <hip/hip_runtime.h>

#define TT 8192
#define DD 1024
#define HH 2816
#define NE 8
#define NP2 (2 * HH)  // 5632 interleaved w1/w3 rows per expert

typedef unsigned short u16;
typedef unsigned int u32;
typedef __attribute__((ext_vector_type(8))) short short8;
typedef __attribute__((ext_vector_type(4))) float floatx4;

__device__ __forceinline__ u16 f2b(float f) {
  unsigned u = __float_as_uint(f);
  unsigned r = u + 0x7fffu + ((u >> 16) & 1u);
  return (u16)(r >> 16);
}
__device__ __forceinline__ float b2f(u16 v) { return __uint_as_float(((u32)v) << 16); }

// async global->LDS, 16B per lane; LDS dest = wave-uniform base + lane*16
__device__ __forceinline__ void gl16(const u16* g, u16* l) {
  __builtin_amdgcn_global_load_lds(
      (const __attribute__((address_space(1))) u32*)g,
      (__attribute__((address_space(3))) u32*)l, 16, 0, 0);
}

// ---------------- fp32 -> bf16, single array ----------------
__global__ void cvt1_kernel(const float* __restrict__ src, u16* __restrict__ dst, int n4) {
  int i = blockIdx.x * blockDim.x + threadIdx.x;
  if (i >= n4) return;
  float4 v = ((const float4*)src)[i];
  ushort4 o;
  o.x = f2b(v.x); o.y = f2b(v.y); o.z = f2b(v.z); o.w = f2b(v.w);
  ((ushort4*)dst)[i] = o;
}

// ---------------- w1/w3 -> interleaved bf16 w13 buffer ----------------
// w13[e] row n': group g=n'>>5; (n'&16)==0 -> w1 row h, ==16 -> w3 row h; h = g*16 + (n'&15)
__global__ void cvtw13_kernel(const float* __restrict__ w1, const float* __restrict__ w3,
                              const float* __restrict__ sw1, const float* __restrict__ sw3,
                              u16* __restrict__ w13) {
  int R = blockIdx.x;             // 0 .. 9*NP2-1
  int E = R / NP2;
  int np = R - E * NP2;
  int h = ((np >> 5) << 4) | (np & 15);
  int which = (np >> 4) & 1;
  const float* src;
  if (E < 8) src = (which ? w3 : w1) + ((size_t)E * HH + h) * DD;
  else       src = (which ? sw3 : sw1) + (size_t)h * DD;
  float4 v = ((const float4*)src)[threadIdx.x];
  ushort4 o;
  o.x = f2b(v.x); o.y = f2b(v.y); o.z = f2b(v.z); o.w = f2b(v.w);
  ((ushort4*)(w13 + (size_t)R * DD))[threadIdx.x] = o;
}

// ---------------- gate ----------------
__global__ void gate_kernel(const float* __restrict__ x, const float* __restrict__ gw,
                            int* __restrict__ cnt, int* __restrict__ slots,
                            int* __restrict__ tok2slot, float* __restrict__ tok2wgt) {
  int t = blockIdx.x;
  int l = threadIdx.x;  // 64 threads = 1 wave
  const float4* xr = (const float4*)(x + (size_t)t * DD);
  float acc[NE];
#pragma unroll
  for (int e = 0; e < NE; ++e) acc[e] = 0.f;
#pragma unroll
  for (int c = 0; c < 4; ++c) {
    float4 xv = xr[l + c * 64];
#pragma unroll
    for (int e = 0; e < NE; ++e) {
      float4 g = ((const float4*)(gw + e * DD))[l + c * 64];
      acc[e] += xv.x * g.x + xv.y * g.y + xv.z * g.z + xv.w * g.w;
    }
  }
#pragma unroll
  for (int e = 0; e < NE; ++e)
    for (int off = 32; off > 0; off >>= 1)
      acc[e] += __shfl_xor(acc[e], off);
  if (l == 0) {
    float m = acc[0];
#pragma unroll
    for (int e = 1; e < NE; ++e) m = fmaxf(m, acc[e]);
    float p[NE]; float s = 0.f;
#pragma unroll
    for (int e = 0; e < NE; ++e) { p[e] = __expf(acc[e] - m); s += p[e]; }
#pragma unroll
    for (int e = 0; e < NE; ++e) p[e] /= s;
    int i1 = 0;
    for (int e = 1; e < NE; ++e) if (p[e] > p[i1]) i1 = e;
    int i2 = (i1 == 0) ? 1 : 0;
    for (int e = 0; e < NE; ++e) if (e != i1 && p[e] > p[i2]) i2 = e;
    float d = p[i1] + p[i2] + 1e-20f;
    float wa = p[i1] / d, wb = p[i2] / d;
    int p1 = atomicAdd(&cnt[i1], 1);
    slots[i1 * TT + p1] = t;
    int p2 = atomicAdd(&cnt[i2], 1);
    slots[i2 * TT + p2] = t;
    tok2slot[2 * t] = i1 * TT + p1;  tok2wgt[2 * t] = wa;
    tok2slot[2 * t + 1] = i2 * TT + p2;  tok2wgt[2 * t + 1] = wb;
  }
}

// ---------------- scan + tilemaps (128-granule for ffn2, 256-granule for ffn1) ----------------
__global__ void scan_kernel(int* __restrict__ cnt, int* __restrict__ basep,
                            int* __restrict__ tilemap, int* __restrict__ tilemap256) {
  cnt[8] = TT;
  int s = 0, idx = 0, idx2 = 0;
  for (int e = 0; e < 9; ++e) {
    basep[e] = s;
    int ne = cnt[e];
    int nt = (ne + 127) >> 7;
    for (int rt = 0; rt < nt; ++rt) tilemap[idx++] = e | (rt << 8);
    int nt2 = (ne + 255) >> 8;
    for (int rt = 0; rt < nt2; ++rt) tilemap256[idx2++] = e | (rt << 8);
    s += ne;
  }
  basep[9] = s;
  for (int i = idx; i < 255; ++i) tilemap[i] = -1;
  tilemap[255] = idx;
  for (int i = idx2; i < 104; ++i) tilemap256[i] = -1;
}

// ---------------- gather x rows (fp32 -> bf16, compacted; exact 3*TT rows) ----------------
__global__ void gatherx_kernel(const float* __restrict__ x, const int* __restrict__ basep,
                               const int* __restrict__ slots, u16* __restrict__ xg) {
  int r = blockIdx.x * 2 + (threadIdx.x >> 7);  // global compact row in [0, 3*TT)
  int e = 0;
#pragma unroll
  for (int k = 1; k < 9; ++k) e += (r >= basep[k]);
  int p = r - basep[e];
  int tok = (e < 8) ? slots[e * TT + p] : p;
  int lane = threadIdx.x & 127;
  const float4* src = (const float4*)(x + (size_t)tok * DD) + lane * 2;
  float4 v0 = src[0], v1 = src[1];
  ushort4 o0, o1;
  o0.x = f2b(v0.x); o0.y = f2b(v0.y); o0.z = f2b(v0.z); o0.w = f2b(v0.w);
  o1.x = f2b(v1.x); o1.y = f2b(v1.y); o1.z = f2b(v1.z); o1.w = f2b(v1.w);
  ushort4* dp = (ushort4*)(xg + (size_t)r * DD) + lane * 2;
  dp[0] = o0; dp[1] = o1;
}

// ---------------- FFN stage 1: 256x256xBK64, 8 waves, 4-phase dbuf schedule ----------------
// B = interleaved w13; fused SwiGLU epilogue pairs adjacent n-fragments (same lanes).
__global__ __launch_bounds__(512, 2) void ffn1_kernel(
    const u16* __restrict__ xg, const u16* __restrict__ w13,
    const int* __restrict__ cnt, const int* __restrict__ basep,
    const int* __restrict__ tm256, u16* __restrict__ hbuf) {
  // XCD-aware swizzle: grid 22x104 = 2288 = 8*286
  int d = blockIdx.y * 22 + blockIdx.x;
  int ord = (d & 7) * 286 + (d >> 3);
  int bx = ord % 22, by = ord / 22;
  int tmv = tm256[by];
  if (tmv < 0) return;
  int e = tmv & 255, rt = tmv >> 8;
  int ne = (e < 8) ? cnt[e] : TT;
  int row0 = basep[e] + rt * 256;
  int c0 = bx * 256;

  __shared__ u16 sA[2][256 * 64];
  __shared__ u16 sB[2][256 * 64];

  int tid = threadIdx.x;
  int wv = tid >> 6, l = tid & 63;
  int wm = wv >> 2, wn = wv & 3;
  int lo = l & 15, hi = l >> 4;

  const u16* Abase = xg + (size_t)row0 * DD;
  const u16* Bbase = w13 + (size_t)e * NP2 * DD + (size_t)c0 * DD;

  // staging granule idx = q*512 + tid -> row = q*64 + (tid>>3), slot = tid&7;
  // source k-granule = slot ^ ((row>>1)&7) = (tid&7) ^ ((tid>>4)&7)   [q-independent]
  int srow = tid >> 3;
  int sg = (tid & 7) ^ ((tid >> 4) & 7);
  const u16* pa0 = Abase + (size_t)srow * DD + sg * 8;
  const u16* pb0 = Bbase + (size_t)srow * DD + sg * 8;
  int lbase = wv * 512;  // elements; wave-uniform; per-q stride 4096 elements

  // prologue: stage K-tile 0 into buf 0
#pragma unroll
  for (int q = 0; q < 4; ++q) gl16(pa0 + (size_t)q * 64 * DD, &sA[0][0] + lbase + q * 4096);
#pragma unroll
  for (int q = 0; q < 4; ++q) gl16(pb0 + (size_t)q * 64 * DD, &sB[0][0] + lbase + q * 4096);
  pa0 += 64; pb0 += 64;
  asm volatile("s_waitcnt vmcnt(0)" ::: "memory");
  __builtin_amdgcn_s_barrier();

  floatx4 acc[8][4];
#pragma unroll
  for (int i = 0; i < 8; ++i)
#pragma unroll
    for (int j = 0; j < 4; ++j) acc[i][j] = (floatx4){0.f, 0.f, 0.f, 0.f};

  // fragment LDS offsets (elements): row*64 + ((hi ^ (lo>>1))*8); kk1 = XOR 32
  int aoff0 = (wm * 128 + lo) * 64 + ((hi ^ (lo >> 1)) * 8);
  int boff0 = (wn * 64 + lo) * 64 + ((hi ^ (lo >> 1)) * 8);

  int buf = 0;
#pragma unroll 1
  for (int kt = 0; kt < 16; ++kt) {
    const u16* sac = &sA[buf][0];
    const u16* sbc = &sB[buf][0];
    u16* san = &sA[buf ^ 1][0];
    u16* sbn = &sB[buf ^ 1][0];
    short8 af[4], bf[4];

    // ---- phase 0: prefetch A(kt+1); read A(mi0-3,kk0)+B(kk0); 16 MFMA
    if (kt < 15) {
#pragma unroll
      for (int q = 0; q < 4; ++q) gl16(pa0 + (size_t)q * 64 * DD, san + lbase + q * 4096);
      pa0 += 64;
    }
#pragma unroll
    for (int mi = 0; mi < 4; ++mi) af[mi] = *(const short8*)(sac + aoff0 + mi * 1024);
#pragma unroll
    for (int ni = 0; ni < 4; ++ni) bf[ni] = *(const short8*)(sbc + boff0 + ni * 1024);
    __builtin_amdgcn_s_barrier();
    __builtin_amdgcn_s_setprio(1);
#pragma unroll
    for (int mi = 0; mi < 4; ++mi)
#pragma unroll
      for (int ni = 0; ni < 4; ++ni)
        acc[mi][ni] = __builtin_amdgcn_mfma_f32_16x16x32_bf16(af[mi], bf[ni], acc[mi][ni], 0, 0, 0);
    __builtin_amdgcn_s_setprio(0);
    __builtin_amdgcn_s_barrier();

    // ---- phase 1: prefetch B(kt+1); read A(mi4-7,kk0); 16 MFMA (reuse bf)
    if (kt < 15) {
#pragma unroll
      for (int q = 0; q < 4; ++q) gl16(pb0 + (size_t)q * 64 * DD, sbn + lbase + q * 4096);
      pb0 += 64;
    }
#pragma unroll
    for (int mi = 0; mi < 4; ++mi) af[mi] = *(const short8*)(sac + aoff0 + (mi + 4) * 1024);
    __builtin_amdgcn_s_barrier();
    __builtin_amdgcn_s_setprio(1);
#pragma unroll
    for (int mi = 0; mi < 4; ++mi)
#pragma unroll
      for (int ni = 0; ni < 4; ++ni)
        acc[mi + 4][ni] = __builtin_amdgcn_mfma_f32_16x16x32_bf16(af[mi], bf[ni], acc[mi + 4][ni], 0, 0, 0);
    __builtin_amdgcn_s_setprio(0);
    __builtin_amdgcn_s_barrier();

    // ---- phase 2: read A(mi0-3,kk1)+B(kk1); 16 MFMA
#pragma unroll
    for (int mi = 0; mi < 4; ++mi) af[mi] = *(const short8*)(sac + (aoff0 ^ 32) + mi * 1024);
#pragma unroll
    for (int ni = 0; ni < 4; ++ni) bf[ni] = *(const short8*)(sbc + (boff0 ^ 32) + ni * 1024);
    __builtin_amdgcn_s_barrier();
    __builtin_amdgcn_s_setprio(1);
#pragma unroll
    for (int mi = 0; mi < 4; ++mi)
#pragma unroll
      for (int ni = 0; ni < 4; ++ni)
        acc[mi][ni] = __builtin_amdgcn_mfma_f32_16x16x32_bf16(af[mi], bf[ni], acc[mi][ni], 0, 0, 0);
    __builtin_amdgcn_s_setprio(0);
    __builtin_amdgcn_s_barrier();

    // ---- phase 3: read A(mi4-7,kk1); 16 MFMA; per-wave drain; tile barrier
#pragma unroll
    for (int mi = 0; mi < 4; ++mi) af[mi] = *(const short8*)(sac + (aoff0 ^ 32) + (mi + 4) * 1024);
    __builtin_amdgcn_s_barrier();
    __builtin_amdgcn_s_setprio(1);
#pragma unroll
    for (int mi = 0; mi < 4; ++mi)
#pragma unroll
      for (int ni = 0; ni < 4; ++ni)
        acc[mi + 4][ni] = __builtin_amdgcn_mfma_f32_16x16x32_bf16(af[mi], bf[ni], acc[mi + 4][ni], 0, 0, 0);
    __builtin_amdgcn_s_setprio(0);
    asm volatile("s_waitcnt vmcnt(0)" ::: "memory");
    __builtin_amdgcn_s_barrier();
    buf ^= 1;
  }

  // epilogue: pair (ni even = v1, ni odd = v3) -> silu(v1)*v3, in-lane
  int hbase = (c0 + wn * 64) >> 1;
#pragma unroll
  for (int mi = 0; mi < 8; ++mi) {
#pragma unroll
    for (int np = 0; np < 2; ++np) {
      floatx4 v1 = acc[mi][np * 2], v3 = acc[mi][np * 2 + 1];
      int hcol = hbase + np * 16 + lo;
#pragma unroll
      for (int r = 0; r < 4; ++r) {
        int row = wm * 128 + mi * 16 + hi * 4 + r;
        if (rt * 256 + row < ne) {
          float a = v1[r];
          float hval = a / (1.f + __expf(-a)) * v3[r];
          hbuf[(size_t)(row0 + row) * HH + hcol] = f2b(hval);
        }
      }
    }
  }
}

// ---------------- FFN stage 2: y = h @ w2^T (unweighted, bf16) ----------------
__global__ __launch_bounds__(256, 2) void ffn2_kernel(
    const u16* __restrict__ hbuf, const u16* __restrict__ w2b,
    const int* __restrict__ cnt, const int* __restrict__ basep,
    const int* __restrict__ tilemap, u16* __restrict__ ybuf) {
  // XCD-aware swizzle: grid 8x200 = 1600 = 8*200
  int d = blockIdx.y * 8 + blockIdx.x;
  int ord = (d & 7) * 200 + (d >> 3);
  int bxn = ord & 7, byn = ord >> 3;
  int tm = tilemap[byn];
  if (tm < 0) return;
  int e = tm & 255, rt = tm >> 8;
  int ne = (e < 8) ? cnt[e] : TT;
  int c0 = bxn * 128;
  int tid = threadIdx.x;
  int wv = tid >> 6, l = tid & 63;

  __shared__ u16 sA[128 * 32];
  __shared__ u16 sB[128 * 32];

  int row0 = basep[e] + rt * 128;
  const u16* Ab = hbuf + (size_t)row0 * HH;
  const u16* Bb = w2b + (size_t)e * DD * HH + (size_t)c0 * HH;

  int g0 = wv * 64 + l, g1 = 256 + g0;
  int r0 = g0 >> 2, cs0 = ((g0 & 3) ^ ((r0 >> 1) & 3)) * 8;
  int r1 = g1 >> 2, cs1 = ((g1 & 3) ^ ((r1 >> 1) & 3)) * 8;
  const u16* pA0 = Ab + (size_t)r0 * HH + cs0;
  const u16* pA1 = Ab + (size_t)r1 * HH + cs1;
  const u16* pB0 = Bb + (size_t)r0 * HH + cs0;
  const u16* pB1 = Bb + (size_t)r1 * HH + cs1;
  u16* dA0 = sA + wv * 512;  u16* dA1 = sA + 2048 + wv * 512;
  u16* dB0 = sB + wv * 512;  u16* dB1 = sB + 2048 + wv * 512;

  int wm = wv & 1, wn = wv >> 1;
  int lo = l & 15, hi = l >> 4;
  int sw8 = (hi ^ ((lo >> 1) & 3)) * 8;
  int aoff = (wm * 64 + lo) * 32 + sw8;
  int boff = (wn * 64 + lo) * 32 + sw8;

  floatx4 acc[4][4];
#pragma unroll
  for (int i = 0; i < 4; ++i)
#pragma unroll
    for (int j = 0; j < 4; ++j) acc[i][j] = (floatx4){0.f, 0.f, 0.f, 0.f};

  for (int kt = 0; kt < HH / 32; ++kt) {
    gl16(pA0, dA0); gl16(pA1, dA1);
    gl16(pB0, dB0); gl16(pB1, dB1);
    pA0 += 32; pA1 += 32; pB0 += 32; pB1 += 32;
    __syncthreads();

    short8 af[4], bf[4];
#pragma unroll
    for (int mi = 0; mi < 4; ++mi)
      af[mi] = *(const short8*)(sA + aoff + mi * 512);
#pragma unroll
    for (int ni = 0; ni < 4; ++ni)
      bf[ni] = *(const short8*)(sB + boff + ni * 512);
#pragma unroll
    for (int mi = 0; mi < 4; ++mi)
#pragma unroll
      for (int ni = 0; ni < 4; ++ni)
        acc[mi][ni] = __builtin_amdgcn_mfma_f32_16x16x32_bf16(af[mi], bf[ni], acc[mi][ni], 0, 0, 0);
    __syncthreads();
  }

#pragma unroll
  for (int mi = 0; mi < 4; ++mi)
#pragma unroll
    for (int ni = 0; ni < 4; ++ni)
#pragma unroll
      for (int r = 0; r < 4; ++r) {
        int row = wm * 64 + mi * 16 + hi * 4 + r;
        if (rt * 128 + row < ne) {
          int col = c0 + wn * 64 + ni * 16 + lo;
          ybuf[(size_t)(row0 + row) * DD + col] = f2b(acc[mi][ni][r]);
        }
      }
}

// ---------------- combine: out[t] = w0*y[s0] + w1*y[s1] + y[shared] ----------------
__global__ void combine_kernel(const u16* __restrict__ ybuf, const int* __restrict__ tok2slot,
                               const float* __restrict__ tok2wgt, const int* __restrict__ basep,
                               float* __restrict__ out) {
  int idx = blockIdx.x * 256 + threadIdx.x;  // TT*DD/8 threads
  int t = idx >> 7;
  int c = (idx & 127) * 8;
  int e0 = tok2slot[2 * t], e1 = tok2slot[2 * t + 1];
  float w0 = tok2wgt[2 * t], w1 = tok2wgt[2 * t + 1];
  int rr0 = basep[e0 >> 13] + (e0 & 8191);
  int rr1 = basep[e1 >> 13] + (e1 & 8191);
  int rs = 2 * TT + t;
  const ushort4* y0p = (const ushort4*)(ybuf + (size_t)rr0 * DD + c);
  const ushort4* y1p = (const ushort4*)(ybuf + (size_t)rr1 * DD + c);
  const ushort4* ysp = (const ushort4*)(ybuf + (size_t)rs * DD + c);
  float4* op = (float4*)(out + (size_t)t * DD + c);
#pragma unroll
  for (int q = 0; q < 2; ++q) {
    ushort4 a = y0p[q], b = y1p[q], s = ysp[q];
    float4 o;
    o.x = w0 * b2f(a.x) + w1 * b2f(b.x) + b2f(s.x);
    o.y = w0 * b2f(a.y) + w1 * b2f(b.y) + b2f(s.y);
    o.z = w0 * b2f(a.z) + w1 * b2f(b.z) + b2f(s.z);
    o.w = w0 * b2f(a.w) + w1 * b2f(b.w) + b2f(s.w);
    op[q] = o;
  }
}

extern "C" void kernel_launch(void* const* d_in, const int* in_sizes, int n_in,
                              void* d_out, int out_size, void* d_ws, size_t ws_size,
                              hipStream_t stream) {
  const float* x   = (const float*)d_in[0];
  const float* gw  = (const float*)d_in[1];
  const float* w1  = (const float*)d_in[2];
  const float* w2  = (const float*)d_in[3];
  const float* w3  = (const float*)d_in[4];
  const float* sw1 = (const float*)d_in[5];
  const float* sw2 = (const float*)d_in[6];
  const float* sw3 = (const float*)d_in[7];
  float* out = (float*)d_out;

  char* ws = (char*)d_ws;
  size_t off = 0;
  int* cnt = (int*)(ws + off);      off += 256;
  int* basep = (int*)(ws + off);    off += 256;
  int* tilemap = (int*)(ws + off);  off += 1024;
  int* tilemap256 = (int*)(ws + off); off += 512;
  int* slots = (int*)(ws + off);    off += (size_t)8 * TT * 4;
  int* tok2slot = (int*)(ws + off); off += (size_t)2 * TT * 4;
  float* tok2wgt = (float*)(ws + off); off += (size_t)2 * TT * 4;
  off = (off + 1023) & ~(size_t)1023;
  const size_t WSZ = (size_t)9 * HH * DD;     // elements per (single) weight buffer
  u16* w13 = (u16*)(ws + off); off += (size_t)2 * WSZ * 2;  // interleaved w1/w3
  u16* w2b = (u16*)(ws + off); off += WSZ * 2;
  u16* xg  = (u16*)(ws + off); off += (size_t)3 * TT * DD * 2;  // aliased as ybuf after ffn1
  u16* hbuf = (u16*)(ws + off); off += (size_t)3 * TT * HH * 2;
  u16* ybuf = xg;  // xg dead after ffn1; reuse for ffn2 output

  hipMemsetAsync(cnt, 0, 64, stream);

  const int b = 256;
  cvtw13_kernel<<<9 * NP2, b, 0, stream>>>(w1, w3, sw1, sw3, w13);
  int nw2 = 8 * DD * HH / 4;
  cvt1_kernel<<<(nw2 + b - 1) / b, b, 0, stream>>>(w2, w2b, nw2);
  int ns2 = DD * HH / 4;
  cvt1_kernel<<<(ns2 + b - 1) / b, b, 0, stream>>>(sw2, w2b + (size_t)8 * DD * HH, ns2);

  gate_kernel<<<TT, 64, 0, stream>>>(x, gw, cnt, slots, tok2slot, tok2wgt);
  scan_kernel<<<1, 1, 0, stream>>>(cnt, basep, tilemap, tilemap256);
  gatherx_kernel<<<3 * TT / 2, 256, 0, stream>>>(x, basep, slots, xg);

  ffn1_kernel<<<dim3(22, 104), 512, 0, stream>>>(xg, w13, cnt, basep, tilemap256, hbuf);
  ffn2_kernel<<<dim3(DD / 128, 200), 256, 0, stream>>>(hbuf, w2b, cnt, basep, tilemap, ybuf);
  combine_kernel<<<TT * DD / 8 / 256, 256, 0, stream>>>(ybuf, tok2slot, tok2wgt, basep, out);
}

// Round 3
// 1072.668 us; speedup vs baseline: 1.0509x; 1.0509x over previous
//
#include <hip/hip_runtime.h>

#define TT 8192
#define DD 1024
#define HH 2816
#define NE 8
#define NP2 (2 * HH)  // 5632 interleaved w1/w3 rows per expert

typedef unsigned short u16;
typedef unsigned int u32;
typedef __attribute__((ext_vector_type(8))) short short8;
typedef __attribute__((ext_vector_type(4))) float floatx4;

__device__ __forceinline__ u16 f2b(float f) {
  unsigned u = __float_as_uint(f);
  unsigned r = u + 0x7fffu + ((u >> 16) & 1u);
  return (u16)(r >> 16);
}
__device__ __forceinline__ float b2f(u16 v) { return __uint_as_float(((u32)v) << 16); }

// async global->LDS, 16B per lane; LDS dest = wave-uniform base + lane*16
__device__ __forceinline__ void gl16(const u16* g, u16* l) {
  __builtin_amdgcn_global_load_lds(
      (const __attribute__((address_space(1))) u32*)g,
      (__attribute__((address_space(3))) u32*)l, 16, 0, 0);
}

// ---------------- fp32 -> bf16, single array ----------------
__global__ void cvt1_kernel(const float* __restrict__ src, u16* __restrict__ dst, int n4) {
  int i = blockIdx.x * blockDim.x + threadIdx.x;
  if (i >= n4) return;
  float4 v = ((const float4*)src)[i];
  ushort4 o;
  o.x = f2b(v.x); o.y = f2b(v.y); o.z = f2b(v.z); o.w = f2b(v.w);
  ((ushort4*)dst)[i] = o;
}

// ---------------- w1/w3 -> interleaved bf16 w13 buffer ----------------
// w13[e] row n': group g=n'>>5; (n'&16)==0 -> w1 row h, ==16 -> w3 row h; h = g*16 + (n'&15)
__global__ void cvtw13_kernel(const float* __restrict__ w1, const float* __restrict__ w3,
                              const float* __restrict__ sw1, const float* __restrict__ sw3,
                              u16* __restrict__ w13) {
  int R = blockIdx.x;             // 0 .. 9*NP2-1
  int E = R / NP2;
  int np = R - E * NP2;
  int h = ((np >> 5) << 4) | (np & 15);
  int which = (np >> 4) & 1;
  const float* src;
  if (E < 8) src = (which ? w3 : w1) + ((size_t)E * HH + h) * DD;
  else       src = (which ? sw3 : sw1) + (size_t)h * DD;
  float4 v = ((const float4*)src)[threadIdx.x];
  ushort4 o;
  o.x = f2b(v.x); o.y = f2b(v.y); o.z = f2b(v.z); o.w = f2b(v.w);
  ((ushort4*)(w13 + (size_t)R * DD))[threadIdx.x] = o;
}

// ---------------- gate ----------------
__global__ void gate_kernel(const float* __restrict__ x, const float* __restrict__ gw,
                            int* __restrict__ cnt, int* __restrict__ slots,
                            int* __restrict__ tok2slot, float* __restrict__ tok2wgt) {
  int t = blockIdx.x;
  int l = threadIdx.x;  // 64 threads = 1 wave
  const float4* xr = (const float4*)(x + (size_t)t * DD);
  float acc[NE];
#pragma unroll
  for (int e = 0; e < NE; ++e) acc[e] = 0.f;
#pragma unroll
  for (int c = 0; c < 4; ++c) {
    float4 xv = xr[l + c * 64];
#pragma unroll
    for (int e = 0; e < NE; ++e) {
      float4 g = ((const float4*)(gw + e * DD))[l + c * 64];
      acc[e] += xv.x * g.x + xv.y * g.y + xv.z * g.z + xv.w * g.w;
    }
  }
#pragma unroll
  for (int e = 0; e < NE; ++e)
    for (int off = 32; off > 0; off >>= 1)
      acc[e] += __shfl_xor(acc[e], off);
  if (l == 0) {
    float m = acc[0];
#pragma unroll
    for (int e = 1; e < NE; ++e) m = fmaxf(m, acc[e]);
    float p[NE]; float s = 0.f;
#pragma unroll
    for (int e = 0; e < NE; ++e) { p[e] = __expf(acc[e] - m); s += p[e]; }
#pragma unroll
    for (int e = 0; e < NE; ++e) p[e] /= s;
    int i1 = 0;
    for (int e = 1; e < NE; ++e) if (p[e] > p[i1]) i1 = e;
    int i2 = (i1 == 0) ? 1 : 0;
    for (int e = 0; e < NE; ++e) if (e != i1 && p[e] > p[i2]) i2 = e;
    float d = p[i1] + p[i2] + 1e-20f;
    float wa = p[i1] / d, wb = p[i2] / d;
    int p1 = atomicAdd(&cnt[i1], 1);
    slots[i1 * TT + p1] = t;
    int p2 = atomicAdd(&cnt[i2], 1);
    slots[i2 * TT + p2] = t;
    tok2slot[2 * t] = i1 * TT + p1;  tok2wgt[2 * t] = wa;
    tok2slot[2 * t + 1] = i2 * TT + p2;  tok2wgt[2 * t + 1] = wb;
  }
}

// ---------------- scan + tilemaps (128-granule for ffn2, 256-granule for ffn1) ----------------
__global__ void scan_kernel(int* __restrict__ cnt, int* __restrict__ basep,
                            int* __restrict__ tilemap, int* __restrict__ tilemap256) {
  cnt[8] = TT;
  int s = 0, idx = 0, idx2 = 0;
  for (int e = 0; e < 9; ++e) {
    basep[e] = s;
    int ne = cnt[e];
    int nt = (ne + 127) >> 7;
    for (int rt = 0; rt < nt; ++rt) tilemap[idx++] = e | (rt << 8);
    int nt2 = (ne + 255) >> 8;
    for (int rt = 0; rt < nt2; ++rt) tilemap256[idx2++] = e | (rt << 8);
    s += ne;
  }
  basep[9] = s;
  for (int i = idx; i < 255; ++i) tilemap[i] = -1;
  tilemap[255] = idx;
  for (int i = idx2; i < 104; ++i) tilemap256[i] = -1;
}

// ---------------- gather x rows (fp32 -> bf16, compacted; exact 3*TT rows) ----------------
__global__ void gatherx_kernel(const float* __restrict__ x, const int* __restrict__ basep,
                               const int* __restrict__ slots, u16* __restrict__ xg) {
  int r = blockIdx.x * 2 + (threadIdx.x >> 7);  // global compact row in [0, 3*TT)
  int e = 0;
#pragma unroll
  for (int k = 1; k < 9; ++k) e += (r >= basep[k]);
  int p = r - basep[e];
  int tok = (e < 8) ? slots[e * TT + p] : p;
  int lane = threadIdx.x & 127;
  const float4* src = (const float4*)(x + (size_t)tok * DD) + lane * 2;
  float4 v0 = src[0], v1 = src[1];
  ushort4 o0, o1;
  o0.x = f2b(v0.x); o0.y = f2b(v0.y); o0.z = f2b(v0.z); o0.w = f2b(v0.w);
  o1.x = f2b(v1.x); o1.y = f2b(v1.y); o1.z = f2b(v1.z); o1.w = f2b(v1.w);
  ushort4* dp = (ushort4*)(xg + (size_t)r * DD) + lane * 2;
  dp[0] = o0; dp[1] = o1;
}

// ---------------- FFN stage 1: 256x256xBK64, 8 waves, counted-vmcnt chunk pipeline ----------
// LDS chunks of 16KiB = (A|B) x (32-k-half) x 256 rows; one chunk staged per phase in
// consumption order; vmcnt(8) waits (never 0 in steady state) keep 8 loads in flight.
__global__ __launch_bounds__(512, 2) void ffn1_kernel(
    const u16* __restrict__ xg, const u16* __restrict__ w13,
    const int* __restrict__ cnt, const int* __restrict__ basep,
    const int* __restrict__ tm256, u16* __restrict__ hbuf) {
  // XCD-aware swizzle: grid 22x104 = 2288 = 8*286
  int d = blockIdx.y * 22 + blockIdx.x;
  int ord = (d & 7) * 286 + (d >> 3);
  int bx = ord % 22, by = ord / 22;
  int tmv = tm256[by];
  if (tmv < 0) return;
  int e = tmv & 255, rt = tmv >> 8;
  int ne = (e < 8) ? cnt[e] : TT;
  int row0 = basep[e] + rt * 256;
  int c0 = bx * 256;

  // A chunks: [(buf*2+kk)]*8192 elems; B chunks at +32768. Total 128 KiB.
  __shared__ u16 sAB[65536];

  int tid = threadIdx.x;
  int wv = tid >> 6, l = tid & 63;
  int wm = wv >> 2, wn = wv & 3;
  int lo = l & 15, hi = l >> 4;

  const u16* Abase = xg + (size_t)row0 * DD;
  const u16* Bbase = w13 + (size_t)e * NP2 * DD + (size_t)c0 * DD;

  // staging: granule g=tid -> row tid>>2 (and +128), slot tid&3;
  // source col-slot = slot ^ ((row>>1)&3)  (inverse of read swizzle)
  int sr0 = tid >> 2;
  int cs = ((tid & 3) ^ ((tid >> 3) & 3)) * 8;
  const u16* pA = Abase + (size_t)sr0 * DD + cs;
  const u16* pB = Bbase + (size_t)sr0 * DD + cs;
  int ldst0 = wv * 512;  // wave-uniform chunk-local dest (elems); 2nd half at +4096

  auto stageA = [&](int tn, int kk) {
    u16* dst = sAB + (((tn & 1) * 2 + kk) << 13) + ldst0;
    const u16* src = pA + tn * 64 + kk * 32;
    gl16(src, dst);
    gl16(src + (size_t)128 * DD, dst + 4096);
  };
  auto stageB = [&](int tn, int kk) {
    u16* dst = sAB + 32768 + (((tn & 1) * 2 + kk) << 13) + ldst0;
    const u16* src = pB + tn * 64 + kk * 32;
    gl16(src, dst);
    gl16(src + (size_t)128 * DD, dst + 4096);
  };

  // prologue: tile0 (all 4 chunks, consumption order) + tile1 kk0 chunks = 12 loads
  stageA(0, 0); stageB(0, 0); stageA(0, 1); stageB(0, 1); stageA(1, 0); stageB(1, 0);
  asm volatile("s_waitcnt vmcnt(8)" ::: "memory");  // oldest 4 (tile0 kk0) landed
  __builtin_amdgcn_s_barrier();

  floatx4 acc[8][4];
#pragma unroll
  for (int i = 0; i < 8; ++i)
#pragma unroll
    for (int j = 0; j < 4; ++j) acc[i][j] = (floatx4){0.f, 0.f, 0.f, 0.f};

  // fragment offsets within a chunk (elems): row*32 + swizzled 8-slot
  int aoff = (wm * 128 + lo) * 32 + ((hi ^ ((lo >> 1) & 3)) * 8);
  int boff = (wn * 64 + lo) * 32 + ((hi ^ ((lo >> 1) & 3)) * 8);

#pragma unroll 1
  for (int kt = 0; kt < 16; ++kt) {
    const u16* A0 = sAB + (((kt & 1) * 2 + 0) << 13);
    const u16* A1 = sAB + (((kt & 1) * 2 + 1) << 13);
    const u16* B0 = sAB + 32768 + (((kt & 1) * 2 + 0) << 13);
    const u16* B1 = sAB + 32768 + (((kt & 1) * 2 + 1) << 13);
    short8 af[4], bf[4];

    // ---- p0: stage (kt+1)A-kk1; read A0 mi0-3 + B0; MFMA (mi0-3, kk0)
    if (kt < 15) stageA(kt + 1, 1);
#pragma unroll
    for (int mi = 0; mi < 4; ++mi) af[mi] = *(const short8*)(A0 + aoff + mi * 512);
#pragma unroll
    for (int ni = 0; ni < 4; ++ni) bf[ni] = *(const short8*)(B0 + boff + ni * 512);
    __builtin_amdgcn_s_barrier();
    __builtin_amdgcn_s_setprio(1);
#pragma unroll
    for (int mi = 0; mi < 4; ++mi)
#pragma unroll
      for (int ni = 0; ni < 4; ++ni)
        acc[mi][ni] = __builtin_amdgcn_mfma_f32_16x16x32_bf16(af[mi], bf[ni], acc[mi][ni], 0, 0, 0);
    __builtin_amdgcn_s_setprio(0);
    __builtin_amdgcn_s_barrier();

    // ---- p1: stage (kt+1)B-kk1; read A0 mi4-7; MFMA (mi4-7, kk0); wait for (kt)kk1
    if (kt < 15) stageB(kt + 1, 1);
#pragma unroll
    for (int mi = 0; mi < 4; ++mi) af[mi] = *(const short8*)(A0 + aoff + (mi + 4) * 512);
    __builtin_amdgcn_s_barrier();
    __builtin_amdgcn_s_setprio(1);
#pragma unroll
    for (int mi = 0; mi < 4; ++mi)
#pragma unroll
      for (int ni = 0; ni < 4; ++ni)
        acc[mi + 4][ni] = __builtin_amdgcn_mfma_f32_16x16x32_bf16(af[mi], bf[ni], acc[mi + 4][ni], 0, 0, 0);
    __builtin_amdgcn_s_setprio(0);
    if (kt < 15) asm volatile("s_waitcnt vmcnt(8)" ::: "memory");
    else         asm volatile("s_waitcnt vmcnt(0)" ::: "memory");
    __builtin_amdgcn_s_barrier();

    // ---- p2: stage (kt+2)A-kk0; read A1 mi0-3 + B1; MFMA (mi0-3, kk1)
    if (kt < 14) stageA(kt + 2, 0);
#pragma unroll
    for (int mi = 0; mi < 4; ++mi) af[mi] = *(const short8*)(A1 + aoff + mi * 512);
#pragma unroll
    for (int ni = 0; ni < 4; ++ni) bf[ni] = *(const short8*)(B1 + boff + ni * 512);
    __builtin_amdgcn_s_barrier();
    __builtin_amdgcn_s_setprio(1);
#pragma unroll
    for (int mi = 0; mi < 4; ++mi)
#pragma unroll
      for (int ni = 0; ni < 4; ++ni)
        acc[mi][ni] = __builtin_amdgcn_mfma_f32_16x16x32_bf16(af[mi], bf[ni], acc[mi][ni], 0, 0, 0);
    __builtin_amdgcn_s_setprio(0);
    __builtin_amdgcn_s_barrier();

    // ---- p3: stage (kt+2)B-kk0; read A1 mi4-7; MFMA (mi4-7, kk1); wait for (kt+1)kk0
    if (kt < 14) stageB(kt + 2, 0);
#pragma unroll
    for (int mi = 0; mi < 4; ++mi) af[mi] = *(const short8*)(A1 + aoff + (mi + 4) * 512);
    __builtin_amdgcn_s_barrier();
    __builtin_amdgcn_s_setprio(1);
#pragma unroll
    for (int mi = 0; mi < 4; ++mi)
#pragma unroll
      for (int ni = 0; ni < 4; ++ni)
        acc[mi + 4][ni] = __builtin_amdgcn_mfma_f32_16x16x32_bf16(af[mi], bf[ni], acc[mi + 4][ni], 0, 0, 0);
    __builtin_amdgcn_s_setprio(0);
    if (kt < 14)      asm volatile("s_waitcnt vmcnt(8)" ::: "memory");
    else if (kt == 14) asm volatile("s_waitcnt vmcnt(4)" ::: "memory");
    else               asm volatile("s_waitcnt vmcnt(0)" ::: "memory");
    __builtin_amdgcn_s_barrier();
  }

  // epilogue: pair (ni even = v1, ni odd = v3) -> silu(v1)*v3, in-lane
  int hbase = (c0 + wn * 64) >> 1;
#pragma unroll
  for (int mi = 0; mi < 8; ++mi) {
#pragma unroll
    for (int np = 0; np < 2; ++np) {
      floatx4 v1 = acc[mi][np * 2], v3 = acc[mi][np * 2 + 1];
      int hcol = hbase + np * 16 + lo;
#pragma unroll
      for (int r = 0; r < 4; ++r) {
        int row = wm * 128 + mi * 16 + hi * 4 + r;
        if (rt * 256 + row < ne) {
          float a = v1[r];
          float hval = a / (1.f + __expf(-a)) * v3[r];
          hbuf[(size_t)(row0 + row) * HH + hcol] = f2b(hval);
        }
      }
    }
  }
}

// ---------------- FFN stage 2: y = h @ w2^T (unweighted, bf16) ----------------
__global__ __launch_bounds__(256, 2) void ffn2_kernel(
    const u16* __restrict__ hbuf, const u16* __restrict__ w2b,
    const int* __restrict__ cnt, const int* __restrict__ basep,
    const int* __restrict__ tilemap, u16* __restrict__ ybuf) {
  // XCD-aware swizzle: grid 8x200 = 1600 = 8*200
  int d = blockIdx.y * 8 + blockIdx.x;
  int ord = (d & 7) * 200 + (d >> 3);
  int bxn = ord & 7, byn = ord >> 3;
  int tm = tilemap[byn];
  if (tm < 0) return;
  int e = tm & 255, rt = tm >> 8;
  int ne = (e < 8) ? cnt[e] : TT;
  int c0 = bxn * 128;
  int tid = threadIdx.x;
  int wv = tid >> 6, l = tid & 63;

  __shared__ u16 sA[128 * 32];
  __shared__ u16 sB[128 * 32];

  int row0 = basep[e] + rt * 128;
  const u16* Ab = hbuf + (size_t)row0 * HH;
  const u16* Bb = w2b + (size_t)e * DD * HH + (size_t)c0 * HH;

  int g0 = wv * 64 + l, g1 = 256 + g0;
  int r0 = g0 >> 2, cs0 = ((g0 & 3) ^ ((r0 >> 1) & 3)) * 8;
  int r1 = g1 >> 2, cs1 = ((g1 & 3) ^ ((r1 >> 1) & 3)) * 8;
  const u16* pA0 = Ab + (size_t)r0 * HH + cs0;
  const u16* pA1 = Ab + (size_t)r1 * HH + cs1;
  const u16* pB0 = Bb + (size_t)r0 * HH + cs0;
  const u16* pB1 = Bb + (size_t)r1 * HH + cs1;
  u16* dA0 = sA + wv * 512;  u16* dA1 = sA + 2048 + wv * 512;
  u16* dB0 = sB + wv * 512;  u16* dB1 = sB + 2048 + wv * 512;

  int wm = wv & 1, wn = wv >> 1;
  int lo = l & 15, hi = l >> 4;
  int sw8 = (hi ^ ((lo >> 1) & 3)) * 8;
  int aoff = (wm * 64 + lo) * 32 + sw8;
  int boff = (wn * 64 + lo) * 32 + sw8;

  floatx4 acc[4][4];
#pragma unroll
  for (int i = 0; i < 4; ++i)
#pragma unroll
    for (int j = 0; j < 4; ++j) acc[i][j] = (floatx4){0.f, 0.f, 0.f, 0.f};

  for (int kt = 0; kt < HH / 32; ++kt) {
    gl16(pA0, dA0); gl16(pA1, dA1);
    gl16(pB0, dB0); gl16(pB1, dB1);
    pA0 += 32; pA1 += 32; pB0 += 32; pB1 += 32;
    __syncthreads();

    short8 af[4], bf[4];
#pragma unroll
    for (int mi = 0; mi < 4; ++mi)
      af[mi] = *(const short8*)(sA + aoff + mi * 512);
#pragma unroll
    for (int ni = 0; ni < 4; ++ni)
      bf[ni] = *(const short8*)(sB + boff + ni * 512);
#pragma unroll
    for (int mi = 0; mi < 4; ++mi)
#pragma unroll
      for (int ni = 0; ni < 4; ++ni)
        acc[mi][ni] = __builtin_amdgcn_mfma_f32_16x16x32_bf16(af[mi], bf[ni], acc[mi][ni], 0, 0, 0);
    __syncthreads();
  }

#pragma unroll
  for (int mi = 0; mi < 4; ++mi)
#pragma unroll
    for (int ni = 0; ni < 4; ++ni)
#pragma unroll
      for (int r = 0; r < 4; ++r) {
        int row = wm * 64 + mi * 16 + hi * 4 + r;
        if (rt * 128 + row < ne) {
          int col = c0 + wn * 64 + ni * 16 + lo;
          ybuf[(size_t)(row0 + row) * DD + col] = f2b(acc[mi][ni][r]);
        }
      }
}

// ---------------- combine: out[t] = w0*y[s0] + w1*y[s1] + y[shared] ----------------
__global__ void combine_kernel(const u16* __restrict__ ybuf, const int* __restrict__ tok2slot,
                               const float* __restrict__ tok2wgt, const int* __restrict__ basep,
                               float* __restrict__ out) {
  int idx = blockIdx.x * 256 + threadIdx.x;  // TT*DD/8 threads
  int t = idx >> 7;
  int c = (idx & 127) * 8;
  int e0 = tok2slot[2 * t], e1 = tok2slot[2 * t + 1];
  float w0 = tok2wgt[2 * t], w1 = tok2wgt[2 * t + 1];
  int rr0 = basep[e0 >> 13] + (e0 & 8191);
  int rr1 = basep[e1 >> 13] + (e1 & 8191);
  int rs = 2 * TT + t;
  const ushort4* y0p = (const ushort4*)(ybuf + (size_t)rr0 * DD + c);
  const ushort4* y1p = (const ushort4*)(ybuf + (size_t)rr1 * DD + c);
  const ushort4* ysp = (const ushort4*)(ybuf + (size_t)rs * DD + c);
  float4* op = (float4*)(out + (size_t)t * DD + c);
#pragma unroll
  for (int q = 0; q < 2; ++q) {
    ushort4 a = y0p[q], b = y1p[q], s = ysp[q];
    float4 o;
    o.x = w0 * b2f(a.x) + w1 * b2f(b.x) + b2f(s.x);
    o.y = w0 * b2f(a.y) + w1 * b2f(b.y) + b2f(s.y);
    o.z = w0 * b2f(a.z) + w1 * b2f(b.z) + b2f(s.z);
    o.w = w0 * b2f(a.w) + w1 * b2f(b.w) + b2f(s.w);
    op[q] = o;
  }
}

extern "C" void kernel_launch(void* const* d_in, const int* in_sizes, int n_in,
                              void* d_out, int out_size, void* d_ws, size_t ws_size,
                              hipStream_t stream) {
  const float* x   = (const float*)d_in[0];
  const float* gw  = (const float*)d_in[1];
  const float* w1  = (const float*)d_in[2];
  const float* w2  = (const float*)d_in[3];
  const float* w3  = (const float*)d_in[4];
  const float* sw1 = (const float*)d_in[5];
  const float* sw2 = (const float*)d_in[6];
  const float* sw3 = (const float*)d_in[7];
  float* out = (float*)d_out;

  char* ws = (char*)d_ws;
  size_t off = 0;
  int* cnt = (int*)(ws + off);      off += 256;
  int* basep = (int*)(ws + off);    off += 256;
  int* tilemap = (int*)(ws + off);  off += 1024;
  int* tilemap256 = (int*)(ws + off); off += 512;
  int* slots = (int*)(ws + off);    off += (size_t)8 * TT * 4;
  int* tok2slot = (int*)(ws + off); off += (size_t)2 * TT * 4;
  float* tok2wgt = (float*)(ws + off); off += (size_t)2 * TT * 4;
  off = (off + 1023) & ~(size_t)1023;
  const size_t WSZ = (size_t)9 * HH * DD;     // elements per (single) weight buffer
  u16* w13 = (u16*)(ws + off); off += (size_t)2 * WSZ * 2;  // interleaved w1/w3
  u16* w2b = (u16*)(ws + off); off += WSZ * 2;
  u16* xg  = (u16*)(ws + off); off += (size_t)3 * TT * DD * 2;  // aliased as ybuf after ffn1
  u16* hbuf = (u16*)(ws + off); off += (size_t)3 * TT * HH * 2;
  u16* ybuf = xg;  // xg dead after ffn1; reuse for ffn2 output

  hipMemsetAsync(cnt, 0, 64, stream);

  const int b = 256;
  cvtw13_kernel<<<9 * NP2, b, 0, stream>>>(w1, w3, sw1, sw3, w13);
  int nw2 = 8 * DD * HH / 4;
  cvt1_kernel<<<(nw2 + b - 1) / b, b, 0, stream>>>(w2, w2b, nw2);
  int ns2 = DD * HH / 4;
  cvt1_kernel<<<(ns2 + b - 1) / b, b, 0, stream>>>(sw2, w2b + (size_t)8 * DD * HH, ns2);

  gate_kernel<<<TT, 64, 0, stream>>>(x, gw, cnt, slots, tok2slot, tok2wgt);
  scan_kernel<<<1, 1, 0, stream>>>(cnt, basep, tilemap, tilemap256);
  gatherx_kernel<<<3 * TT / 2, 256, 0, stream>>>(x, basep, slots, xg);

  ffn1_kernel<<<dim3(22, 104), 512, 0, stream>>>(xg, w13, cnt, basep, tilemap256, hbuf);
  ffn2_kernel<<<dim3(DD / 128, 200), 256, 0, stream>>>(hbuf, w2b, cnt, basep, tilemap, ybuf);
  combine_kernel<<<TT * DD / 8 / 256, 256, 0, stream>>>(ybuf, tok2slot, tok2wgt, basep, out);
}

// Round 4
// 1060.027 us; speedup vs baseline: 1.0635x; 1.0119x over previous
//
#include <hip/hip_runtime.h>

#define TT 8192
#define DD 1024
#define HH 2816
#define NE 8
#define NP2 (2 * HH)  // 5632 interleaved w1/w3 rows per expert

typedef unsigned short u16;
typedef unsigned int u32;
typedef __attribute__((ext_vector_type(8))) short short8;
typedef __attribute__((ext_vector_type(4))) float floatx4;

__device__ __forceinline__ u16 f2b(float f) {
  unsigned u = __float_as_uint(f);
  unsigned r = u + 0x7fffu + ((u >> 16) & 1u);
  return (u16)(r >> 16);
}
__device__ __forceinline__ float b2f(u16 v) { return __uint_as_float(((u32)v) << 16); }

// async global->LDS, 16B per lane; LDS dest = wave-uniform base + lane*16
__device__ __forceinline__ void gl16(const u16* g, u16* l) {
  __builtin_amdgcn_global_load_lds(
      (const __attribute__((address_space(1))) u32*)g,
      (__attribute__((address_space(3))) u32*)l, 16, 0, 0);
}

// ---------------- fp32 -> bf16, single array ----------------
__global__ void cvt1_kernel(const float* __restrict__ src, u16* __restrict__ dst, int n4) {
  int i = blockIdx.x * blockDim.x + threadIdx.x;
  if (i >= n4) return;
  float4 v = ((const float4*)src)[i];
  ushort4 o;
  o.x = f2b(v.x); o.y = f2b(v.y); o.z = f2b(v.z); o.w = f2b(v.w);
  ((ushort4*)dst)[i] = o;
}

// ---------------- w1/w3 -> interleaved bf16 w13 buffer ----------------
// w13[e] row n': group g=n'>>5; (n'&16)==0 -> w1 row h, ==16 -> w3 row h; h = g*16 + (n'&15)
__global__ void cvtw13_kernel(const float* __restrict__ w1, const float* __restrict__ w3,
                              const float* __restrict__ sw1, const float* __restrict__ sw3,
                              u16* __restrict__ w13) {
  int R = blockIdx.x;             // 0 .. 9*NP2-1
  int E = R / NP2;
  int np = R - E * NP2;
  int h = ((np >> 5) << 4) | (np & 15);
  int which = (np >> 4) & 1;
  const float* src;
  if (E < 8) src = (which ? w3 : w1) + ((size_t)E * HH + h) * DD;
  else       src = (which ? sw3 : sw1) + (size_t)h * DD;
  float4 v = ((const float4*)src)[threadIdx.x];
  ushort4 o;
  o.x = f2b(v.x); o.y = f2b(v.y); o.z = f2b(v.z); o.w = f2b(v.w);
  ((ushort4*)(w13 + (size_t)R * DD))[threadIdx.x] = o;
}

// ---------------- gate ----------------
__global__ void gate_kernel(const float* __restrict__ x, const float* __restrict__ gw,
                            int* __restrict__ cnt, int* __restrict__ slots,
                            int* __restrict__ tok2slot, float* __restrict__ tok2wgt) {
  int t = blockIdx.x;
  int l = threadIdx.x;  // 64 threads = 1 wave
  const float4* xr = (const float4*)(x + (size_t)t * DD);
  float acc[NE];
#pragma unroll
  for (int e = 0; e < NE; ++e) acc[e] = 0.f;
#pragma unroll
  for (int c = 0; c < 4; ++c) {
    float4 xv = xr[l + c * 64];
#pragma unroll
    for (int e = 0; e < NE; ++e) {
      float4 g = ((const float4*)(gw + e * DD))[l + c * 64];
      acc[e] += xv.x * g.x + xv.y * g.y + xv.z * g.z + xv.w * g.w;
    }
  }
#pragma unroll
  for (int e = 0; e < NE; ++e)
    for (int off = 32; off > 0; off >>= 1)
      acc[e] += __shfl_xor(acc[e], off);
  if (l == 0) {
    float m = acc[0];
#pragma unroll
    for (int e = 1; e < NE; ++e) m = fmaxf(m, acc[e]);
    float p[NE]; float s = 0.f;
#pragma unroll
    for (int e = 0; e < NE; ++e) { p[e] = __expf(acc[e] - m); s += p[e]; }
#pragma unroll
    for (int e = 0; e < NE; ++e) p[e] /= s;
    int i1 = 0;
    for (int e = 1; e < NE; ++e) if (p[e] > p[i1]) i1 = e;
    int i2 = (i1 == 0) ? 1 : 0;
    for (int e = 0; e < NE; ++e) if (e != i1 && p[e] > p[i2]) i2 = e;
    float d = p[i1] + p[i2] + 1e-20f;
    float wa = p[i1] / d, wb = p[i2] / d;
    int p1 = atomicAdd(&cnt[i1], 1);
    slots[i1 * TT + p1] = t;
    int p2 = atomicAdd(&cnt[i2], 1);
    slots[i2 * TT + p2] = t;
    tok2slot[2 * t] = i1 * TT + p1;  tok2wgt[2 * t] = wa;
    tok2slot[2 * t + 1] = i2 * TT + p2;  tok2wgt[2 * t + 1] = wb;
  }
}

// ---------------- scan + tilemaps (128-granule legacy, 256-granule for GEMMs) -------------
__global__ void scan_kernel(int* __restrict__ cnt, int* __restrict__ basep,
                            int* __restrict__ tilemap, int* __restrict__ tilemap256) {
  cnt[8] = TT;
  int s = 0, idx = 0, idx2 = 0;
  for (int e = 0; e < 9; ++e) {
    basep[e] = s;
    int ne = cnt[e];
    int nt = (ne + 127) >> 7;
    for (int rt = 0; rt < nt; ++rt) tilemap[idx++] = e | (rt << 8);
    int nt2 = (ne + 255) >> 8;
    for (int rt = 0; rt < nt2; ++rt) tilemap256[idx2++] = e | (rt << 8);
    s += ne;
  }
  basep[9] = s;
  for (int i = idx; i < 255; ++i) tilemap[i] = -1;
  tilemap[255] = idx;
  for (int i = idx2; i < 104; ++i) tilemap256[i] = -1;
}

// ---------------- gather x rows (fp32 -> bf16, compacted; exact 3*TT rows) ----------------
__global__ void gatherx_kernel(const float* __restrict__ x, const int* __restrict__ basep,
                               const int* __restrict__ slots, u16* __restrict__ xg) {
  int r = blockIdx.x * 2 + (threadIdx.x >> 7);  // global compact row in [0, 3*TT)
  int e = 0;
#pragma unroll
  for (int k = 1; k < 9; ++k) e += (r >= basep[k]);
  int p = r - basep[e];
  int tok = (e < 8) ? slots[e * TT + p] : p;
  int lane = threadIdx.x & 127;
  const float4* src = (const float4*)(x + (size_t)tok * DD) + lane * 2;
  float4 v0 = src[0], v1 = src[1];
  ushort4 o0, o1;
  o0.x = f2b(v0.x); o0.y = f2b(v0.y); o0.z = f2b(v0.z); o0.w = f2b(v0.w);
  o1.x = f2b(v1.x); o1.y = f2b(v1.y); o1.z = f2b(v1.z); o1.w = f2b(v1.w);
  ushort4* dp = (ushort4*)(xg + (size_t)r * DD) + lane * 2;
  dp[0] = o0; dp[1] = o1;
}

// ---------------- 256x256xBK64 GEMM template, 8 waves, 2-phase/K-tile counted pipeline ----
// Phase: stage chunk-pair (4 gl16) ; 12 ds_read_b128 ; barrier ; 16 MFMA ; 4 ds_read ;
//        16 MFMA ; counted vmcnt ; barrier.  2 phases (kk0,kk1) per K-tile.
template <int NKT, int LDAB, bool SWIGLU>
__global__ __launch_bounds__(512, 2) void gemm256_kernel(
    const u16* __restrict__ Ag, const u16* __restrict__ Bg, size_t bstride,
    const int* __restrict__ cnt, const int* __restrict__ basep,
    const int* __restrict__ tm256, u16* __restrict__ outb, int nbx, int cpx) {
  // XCD-aware bijective swizzle: total blocks = nbx*104 = 8*cpx
  int d = blockIdx.y * nbx + blockIdx.x;
  int ord = (d & 7) * cpx + (d >> 3);
  int bx = ord % nbx, by = ord / nbx;
  int tmv = tm256[by];
  if (tmv < 0) return;
  int e = tmv & 255, rt = tmv >> 8;
  int ne = (e < 8) ? cnt[e] : TT;
  int row0 = basep[e] + rt * 256;
  int c0 = bx * 256;

  // A chunks: [(buf*2+kk)]*8192 elems; B chunks at +32768. Total 128 KiB.
  __shared__ u16 sAB[65536];

  int tid = threadIdx.x;
  int wv = tid >> 6, l = tid & 63;
  int wm = wv >> 2, wn = wv & 3;
  int lo = l & 15, hi = l >> 4;

  const u16* Abase = Ag + (size_t)row0 * LDAB;
  const u16* Bbase = Bg + (size_t)e * bstride + (size_t)c0 * LDAB;

  // staging: granule g=tid -> row tid>>2 (and +128), slot tid&3;
  // source col-slot = slot ^ ((row>>1)&3)  (inverse of read swizzle)
  int sr0 = tid >> 2;
  int cs = ((tid & 3) ^ ((tid >> 3) & 3)) * 8;
  const u16* pA = Abase + (size_t)sr0 * LDAB + cs;
  const u16* pB = Bbase + (size_t)sr0 * LDAB + cs;
  const u16* pAh = pA + (size_t)128 * LDAB;
  const u16* pBh = pB + (size_t)128 * LDAB;
  int ldst0 = wv * 512;  // wave-uniform chunk-local dest (elems); 2nd half at +4096

  auto stage = [&](int tn, int kk) {
    int slot = ((tn & 1) * 2 + kk) << 13;
    int col = tn * 64 + kk * 32;
    u16* dA = sAB + slot + ldst0;
    u16* dB = dA + 32768;
    gl16(pA + col, dA);
    gl16(pAh + col, dA + 4096);
    gl16(pB + col, dB);
    gl16(pBh + col, dB + 4096);
  };

  // prologue: (0,0) (0,1) (1,0) = 12 loads; ensure (0,0) landed
  stage(0, 0); stage(0, 1);
  if (NKT > 1) stage(1, 0);
  asm volatile("s_waitcnt vmcnt(8)" ::: "memory");
  __builtin_amdgcn_s_barrier();

  floatx4 acc[8][4];
#pragma unroll
  for (int i = 0; i < 8; ++i)
#pragma unroll
    for (int j = 0; j < 4; ++j) acc[i][j] = (floatx4){0.f, 0.f, 0.f, 0.f};

  // fragment offsets within a chunk (elems): row*32 + swizzled 8-slot
  int aoff = (wm * 128 + lo) * 32 + ((hi ^ ((lo >> 1) & 3)) * 8);
  int boff = (wn * 64 + lo) * 32 + ((hi ^ ((lo >> 1) & 3)) * 8);

#pragma unroll 1
  for (int kt = 0; kt < NKT; ++kt) {
    short8 af[4], bf[4];
    // ======== phase P0: consume (kt, kk0) ========
    {
      const u16* A0 = sAB + (((kt & 1) * 2 + 0) << 13);
      const u16* B0 = A0 + 32768;
      if (kt + 1 < NKT) stage(kt + 1, 1);
#pragma unroll
      for (int mi = 0; mi < 4; ++mi) af[mi] = *(const short8*)(A0 + aoff + mi * 512);
#pragma unroll
      for (int ni = 0; ni < 4; ++ni) bf[ni] = *(const short8*)(B0 + boff + ni * 512);
      __builtin_amdgcn_s_barrier();
      __builtin_amdgcn_s_setprio(1);
#pragma unroll
      for (int mi = 0; mi < 4; ++mi)
#pragma unroll
        for (int ni = 0; ni < 4; ++ni)
          acc[mi][ni] = __builtin_amdgcn_mfma_f32_16x16x32_bf16(af[mi], bf[ni], acc[mi][ni], 0, 0, 0);
      __builtin_amdgcn_s_setprio(0);
#pragma unroll
      for (int mi = 0; mi < 4; ++mi) af[mi] = *(const short8*)(A0 + aoff + (mi + 4) * 512);
      __builtin_amdgcn_s_setprio(1);
#pragma unroll
      for (int mi = 0; mi < 4; ++mi)
#pragma unroll
        for (int ni = 0; ni < 4; ++ni)
          acc[mi + 4][ni] = __builtin_amdgcn_mfma_f32_16x16x32_bf16(af[mi], bf[ni], acc[mi + 4][ni], 0, 0, 0);
      __builtin_amdgcn_s_setprio(0);
      if (kt + 1 < NKT) asm volatile("s_waitcnt vmcnt(8)" ::: "memory");
      else              asm volatile("s_waitcnt vmcnt(0)" ::: "memory");
      __builtin_amdgcn_s_barrier();
    }
    // ======== phase P1: consume (kt, kk1) ========
    {
      const u16* A1 = sAB + (((kt & 1) * 2 + 1) << 13);
      const u16* B1 = A1 + 32768;
      if (kt + 2 < NKT) stage(kt + 2, 0);
#pragma unroll
      for (int mi = 0; mi < 4; ++mi) af[mi] = *(const short8*)(A1 + aoff + mi * 512);
#pragma unroll
      for (int ni = 0; ni < 4; ++ni) bf[ni] = *(const short8*)(B1 + boff + ni * 512);
      __builtin_amdgcn_s_barrier();
      __builtin_amdgcn_s_setprio(1);
#pragma unroll
      for (int mi = 0; mi < 4; ++mi)
#pragma unroll
        for (int ni = 0; ni < 4; ++ni)
          acc[mi][ni] = __builtin_amdgcn_mfma_f32_16x16x32_bf16(af[mi], bf[ni], acc[mi][ni], 0, 0, 0);
      __builtin_amdgcn_s_setprio(0);
#pragma unroll
      for (int mi = 0; mi < 4; ++mi) af[mi] = *(const short8*)(A1 + aoff + (mi + 4) * 512);
      __builtin_amdgcn_s_setprio(1);
#pragma unroll
      for (int mi = 0; mi < 4; ++mi)
#pragma unroll
        for (int ni = 0; ni < 4; ++ni)
          acc[mi + 4][ni] = __builtin_amdgcn_mfma_f32_16x16x32_bf16(af[mi], bf[ni], acc[mi + 4][ni], 0, 0, 0);
      __builtin_amdgcn_s_setprio(0);
      if (kt + 2 < NKT)      asm volatile("s_waitcnt vmcnt(8)" ::: "memory");
      else if (kt + 1 < NKT) asm volatile("s_waitcnt vmcnt(4)" ::: "memory");
      else                   asm volatile("s_waitcnt vmcnt(0)" ::: "memory");
      __builtin_amdgcn_s_barrier();
    }
  }

  if constexpr (SWIGLU) {
    // pair (ni even = v1, ni odd = v3) -> silu(v1)*v3, in-lane; out stride HH
    int hbase = (c0 + wn * 64) >> 1;
#pragma unroll
    for (int mi = 0; mi < 8; ++mi) {
#pragma unroll
      for (int np = 0; np < 2; ++np) {
        floatx4 v1 = acc[mi][np * 2], v3 = acc[mi][np * 2 + 1];
        int hcol = hbase + np * 16 + lo;
#pragma unroll
        for (int r = 0; r < 4; ++r) {
          int row = wm * 128 + mi * 16 + hi * 4 + r;
          if (rt * 256 + row < ne) {
            float a = v1[r];
            float hval = a / (1.f + __expf(-a)) * v3[r];
            outb[(size_t)(row0 + row) * HH + hcol] = f2b(hval);
          }
        }
      }
    }
  } else {
#pragma unroll
    for (int mi = 0; mi < 8; ++mi)
#pragma unroll
      for (int ni = 0; ni < 4; ++ni)
#pragma unroll
        for (int r = 0; r < 4; ++r) {
          int row = wm * 128 + mi * 16 + hi * 4 + r;
          if (rt * 256 + row < ne) {
            int col = c0 + wn * 64 + ni * 16 + lo;
            outb[(size_t)(row0 + row) * DD + col] = f2b(acc[mi][ni][r]);
          }
        }
  }
}

// ---------------- combine: out[t] = w0*y[s0] + w1*y[s1] + y[shared] ----------------
__global__ void combine_kernel(const u16* __restrict__ ybuf, const int* __restrict__ tok2slot,
                               const float* __restrict__ tok2wgt, const int* __restrict__ basep,
                               float* __restrict__ out) {
  int idx = blockIdx.x * 256 + threadIdx.x;  // TT*DD/8 threads
  int t = idx >> 7;
  int c = (idx & 127) * 8;
  int e0 = tok2slot[2 * t], e1 = tok2slot[2 * t + 1];
  float w0 = tok2wgt[2 * t], w1 = tok2wgt[2 * t + 1];
  int rr0 = basep[e0 >> 13] + (e0 & 8191);
  int rr1 = basep[e1 >> 13] + (e1 & 8191);
  int rs = 2 * TT + t;
  const ushort4* y0p = (const ushort4*)(ybuf + (size_t)rr0 * DD + c);
  const ushort4* y1p = (const ushort4*)(ybuf + (size_t)rr1 * DD + c);
  const ushort4* ysp = (const ushort4*)(ybuf + (size_t)rs * DD + c);
  float4* op = (float4*)(out + (size_t)t * DD + c);
#pragma unroll
  for (int q = 0; q < 2; ++q) {
    ushort4 a = y0p[q], b = y1p[q], s = ysp[q];
    float4 o;
    o.x = w0 * b2f(a.x) + w1 * b2f(b.x) + b2f(s.x);
    o.y = w0 * b2f(a.y) + w1 * b2f(b.y) + b2f(s.y);
    o.z = w0 * b2f(a.z) + w1 * b2f(b.z) + b2f(s.z);
    o.w = w0 * b2f(a.w) + w1 * b2f(b.w) + b2f(s.w);
    op[q] = o;
  }
}

extern "C" void kernel_launch(void* const* d_in, const int* in_sizes, int n_in,
                              void* d_out, int out_size, void* d_ws, size_t ws_size,
                              hipStream_t stream) {
  const float* x   = (const float*)d_in[0];
  const float* gw  = (const float*)d_in[1];
  const float* w1  = (const float*)d_in[2];
  const float* w2  = (const float*)d_in[3];
  const float* w3  = (const float*)d_in[4];
  const float* sw1 = (const float*)d_in[5];
  const float* sw2 = (const float*)d_in[6];
  const float* sw3 = (const float*)d_in[7];
  float* out = (float*)d_out;

  char* ws = (char*)d_ws;
  size_t off = 0;
  int* cnt = (int*)(ws + off);      off += 256;
  int* basep = (int*)(ws + off);    off += 256;
  int* tilemap = (int*)(ws + off);  off += 1024;
  int* tilemap256 = (int*)(ws + off); off += 512;
  int* slots = (int*)(ws + off);    off += (size_t)8 * TT * 4;
  int* tok2slot = (int*)(ws + off); off += (size_t)2 * TT * 4;
  float* tok2wgt = (float*)(ws + off); off += (size_t)2 * TT * 4;
  off = (off + 1023) & ~(size_t)1023;
  const size_t WSZ = (size_t)9 * HH * DD;     // elements per (single) weight buffer
  u16* w13 = (u16*)(ws + off); off += (size_t)2 * WSZ * 2;  // interleaved w1/w3
  u16* w2b = (u16*)(ws + off); off += WSZ * 2;
  u16* xg  = (u16*)(ws + off); off += (size_t)3 * TT * DD * 2;  // aliased as ybuf after ffn1
  u16* hbuf = (u16*)(ws + off); off += (size_t)3 * TT * HH * 2;
  u16* ybuf = xg;  // xg dead after ffn1; reuse for ffn2 output

  hipMemsetAsync(cnt, 0, 64, stream);

  const int b = 256;
  cvtw13_kernel<<<9 * NP2, b, 0, stream>>>(w1, w3, sw1, sw3, w13);
  int nw2 = 8 * DD * HH / 4;
  cvt1_kernel<<<(nw2 + b - 1) / b, b, 0, stream>>>(w2, w2b, nw2);
  int ns2 = DD * HH / 4;
  cvt1_kernel<<<(ns2 + b - 1) / b, b, 0, stream>>>(sw2, w2b + (size_t)8 * DD * HH, ns2);

  gate_kernel<<<TT, 64, 0, stream>>>(x, gw, cnt, slots, tok2slot, tok2wgt);
  scan_kernel<<<1, 1, 0, stream>>>(cnt, basep, tilemap, tilemap256);
  gatherx_kernel<<<3 * TT / 2, 256, 0, stream>>>(x, basep, slots, xg);

  // ffn1: h = silu(xg @ w13_even^T) * (xg @ w13_odd^T); grid 22x104 = 2288 = 8*286
  gemm256_kernel<DD / 64, DD, true><<<dim3(22, 104), 512, 0, stream>>>(
      xg, w13, (size_t)NP2 * DD, cnt, basep, tilemap256, hbuf, 22, 286);
  // ffn2: y = h @ w2^T; grid 4x104 = 416 = 8*52
  gemm256_kernel<HH / 64, HH, false><<<dim3(4, 104), 512, 0, stream>>>(
      hbuf, w2b, (size_t)DD * HH, cnt, basep, tilemap256, ybuf, 4, 52);

  combine_kernel<<<TT * DD / 8 / 256, 256, 0, stream>>>(ybuf, tok2slot, tok2wgt, basep, out);
}